// Round 9
// baseline (128.652 us; speedup 1.0000x reference)
//
#include <hip/hip_runtime.h>
#include <hip/hip_bf16.h>

#define DIM 128
#define NXCD 8
#define SUBCAP 224              // per (region,xcd) capacity: mean 128 + 8.5 sigma
#define REGCAP (NXCD * SUBCAP)  // 1792 entries per region
#define RSTRIDE 16              // ints per counter (64B: one line per counter)

typedef __attribute__((ext_vector_type(8))) short bf16x8;
typedef __attribute__((ext_vector_type(4))) float f32x4;
typedef __attribute__((ext_vector_type(4))) short short4v;
typedef __attribute__((ext_vector_type(4))) int int4v;

__device__ inline unsigned short f2bf(float f) {
  union { float f; unsigned u; } v; v.f = f;
  return (unsigned short)((v.u + 0x7FFFu + ((v.u >> 16) & 1u)) >> 16);
}
__device__ inline float lo_f(unsigned u) {
  union { unsigned u; float f; } v; v.u = u << 16; return v.f;
}
__device__ inline float hi_f(unsigned u) {
  union { unsigned u; float f; } v; v.u = u & 0xFFFF0000u; return v.f;
}

// ---------------------------------------------------------------------------
// K0: parallel zero of rptr (hipMemsetAsync's fillBufferAligned was 40us of
// launch/latency overhead for 400KB; this is ~2us).
// ---------------------------------------------------------------------------
__global__ __launch_bounds__(256) void zero_kernel(int4v* __restrict__ p, int n4) {
  int i = blockIdx.x * 256 + threadIdx.x;
  if (i < n4) p[i] = (int4v){0, 0, 0, 0};
}

// ---------------------------------------------------------------------------
// K1: partition edges into 64-node dst-regions with XCD-LOCAL sub-lists.
// blockIdx.x&7 proxies the XCD (round-robin dispatch); each (region,xcd)
// sub-list is 14 exact cache lines filled monotonically by one XCD ->
// each line written back once. Entry = (dst&63)<<16 | src.
// ---------------------------------------------------------------------------
__global__ __launch_bounds__(256) void partition_kernel(
    const int* __restrict__ ei, int* __restrict__ rptr,
    unsigned* __restrict__ staging, int E) {
  int e = blockIdx.x * 256 + threadIdx.x;
  if (e >= E) return;
  const int xcd = blockIdx.x & (NXCD - 1);
  unsigned src = (unsigned)ei[e];
  int dst = ei[E + e];
  int r = dst >> 6;
  int slot = atomicAdd(&rptr[(r * NXCD + xcd) * RSTRIDE], 1);
  if (slot < SUBCAP)
    staging[(size_t)r * REGCAP + xcd * SUBCAP + slot] =
        ((unsigned)(dst & 63) << 16) | src;
}

// ---------------------------------------------------------------------------
// K2: per-region merge of 8 sub-lists + in-LDS counting sort -> dst-sorted
// src lists (in place, coalesced writeback) + per-node deg (cnt) and global
// offset (off). One block per region.
// ---------------------------------------------------------------------------
__global__ __launch_bounds__(256) void compact_kernel(
    const int* __restrict__ rptr, unsigned* __restrict__ staging,
    int* __restrict__ cnt, int* __restrict__ off) {
  __shared__ unsigned raw[REGCAP];
  __shared__ unsigned sorted[REGCAP];
  __shared__ int h[64];
  __shared__ int start[64];
  __shared__ int fill[64];
  __shared__ int scnt[NXCD];
  __shared__ int sub0[NXCD];
  const int region = blockIdx.x;
  const int tid = threadIdx.x;
  const size_t base = (size_t)region * REGCAP;

  if (tid < NXCD)
    scnt[tid] = min(rptr[(region * NXCD + tid) * RSTRIDE], SUBCAP);
  if (tid < 64) { h[tid] = 0; fill[tid] = 0; }
  __syncthreads();
  if (tid == 0) {
    int s = 0;
    for (int x = 0; x < NXCD; ++x) { sub0[x] = s; s += scnt[x]; }
  }
  __syncthreads();

  for (int x = 0; x < NXCD; ++x) {
    const int c = scnt[x];
    const int b = sub0[x];
    for (int i = tid; i < c; i += 256) {
      unsigned e = staging[base + x * SUBCAP + i];
      raw[b + i] = e;
      atomicAdd(&h[e >> 16], 1);
    }
  }
  __syncthreads();
  if (tid == 0) {
    int s = 0;
    for (int i = 0; i < 64; ++i) { start[i] = s; s += h[i]; }
  }
  __syncthreads();
  const int total = sub0[NXCD - 1] + scnt[NXCD - 1];
  for (int i = tid; i < total; i += 256) {
    unsigned e = raw[i];
    int d = (int)(e >> 16);
    int pos = start[d] + atomicAdd(&fill[d], 1);
    sorted[pos] = e & 0xFFFFu;  // keep only src
  }
  __syncthreads();
  for (int i = tid; i < total; i += 256) staging[base + i] = sorted[i];
  if (tid < 64) {
    int node = region * 64 + tid;
    cnt[node] = h[tid];
    off[node] = (int)base + start[tid];
  }
}

// ---------------------------------------------------------------------------
// K3: cast x -> bf16 into the x-half of A.  A layout: [mpad][256] bf16,
// k<128 = agg (written by agg_kernel), k>=128 = x.
// ---------------------------------------------------------------------------
__global__ __launch_bounds__(256) void xcast_kernel(
    const float* __restrict__ x, short* __restrict__ A, int nnodes, int mpad) {
  int t = blockIdx.x * 256 + threadIdx.x;
  int node = t >> 5;
  if (node >= mpad) return;
  int c = (t & 31) * 4;
  short4v o = (short4v){0, 0, 0, 0};
  if (node < nnodes) {
    float4 v = *reinterpret_cast<const float4*>(x + (size_t)node * DIM + c);
    o.x = (short)f2bf(v.x); o.y = (short)f2bf(v.y);
    o.z = (short)f2bf(v.z); o.w = (short)f2bf(v.w);
  }
  *reinterpret_cast<short4v*>(A + (size_t)node * 256 + 128 + c) = o;
}

// ---------------------------------------------------------------------------
// K4: mean-aggregation, one wave per node (50048 waves of TLP); gathers bf16
// x-rows from A's x-half (256B coalesced, 4-deep MLP), writes bf16 agg into
// A's agg-half.
// ---------------------------------------------------------------------------
__global__ __launch_bounds__(256) void agg_kernel(
    const int* __restrict__ cnt, const int* __restrict__ off,
    const unsigned* __restrict__ bucket, short* __restrict__ A,
    int nnodes, int mpad) {
  const int wid = (blockIdx.x * 256 + threadIdx.x) >> 6;
  const int lane = threadIdx.x & 63;
  if (wid >= mpad) return;
  unsigned* dst = reinterpret_cast<unsigned*>(A + (size_t)wid * 256) + lane;
  if (wid >= nnodes) { *dst = 0u; return; }
  const int deg  = __builtin_amdgcn_readfirstlane(cnt[wid]);
  const int base = __builtin_amdgcn_readfirstlane(off[wid]);
  const unsigned* xs = reinterpret_cast<const unsigned*>(A) + 64 + lane;

  float a0 = 0.f, b0 = 0.f, a1 = 0.f, b1 = 0.f;
  float a2 = 0.f, b2 = 0.f, a3 = 0.f, b3 = 0.f;
  int j = 0;
  for (; j + 3 < deg; j += 4) {
    const int s0 = __builtin_amdgcn_readfirstlane((int)bucket[base + j]);
    const int s1 = __builtin_amdgcn_readfirstlane((int)bucket[base + j + 1]);
    const int s2 = __builtin_amdgcn_readfirstlane((int)bucket[base + j + 2]);
    const int s3 = __builtin_amdgcn_readfirstlane((int)bucket[base + j + 3]);
    unsigned u0 = xs[(size_t)s0 * 128];
    unsigned u1 = xs[(size_t)s1 * 128];
    unsigned u2 = xs[(size_t)s2 * 128];
    unsigned u3 = xs[(size_t)s3 * 128];
    a0 += lo_f(u0); b0 += hi_f(u0);
    a1 += lo_f(u1); b1 += hi_f(u1);
    a2 += lo_f(u2); b2 += hi_f(u2);
    a3 += lo_f(u3); b3 += hi_f(u3);
  }
  for (; j < deg; ++j) {
    const int s0 = __builtin_amdgcn_readfirstlane((int)bucket[base + j]);
    unsigned u0 = xs[(size_t)s0 * 128];
    a0 += lo_f(u0); b0 += hi_f(u0);
  }
  const float r = 1.0f / fmaxf((float)deg, 1.0f);
  const float av = (a0 + a1 + a2 + a3) * r;
  const float bv = (b0 + b1 + b2 + b3) * r;
  *dst = (unsigned)f2bf(av) | ((unsigned)f2bf(bv) << 16);
}

// ---------------------------------------------------------------------------
// K5: pack B = [[Wl];[Wr]] (256x128) into MFMA fragment order
// ---------------------------------------------------------------------------
__global__ __launch_bounds__(256) void bpack_kernel(
    const float* __restrict__ Wl, const float* __restrict__ Wr,
    short* __restrict__ Bpack) {
  int t = blockIdx.x * 256 + threadIdx.x;
  if (t >= 4096) return;
  int lane = t & 63, nt = (t >> 6) & 7, ks = t >> 9;
  int c = nt * 16 + (lane & 15);
  int kb = ks * 32 + ((lane >> 4) << 3);
  bf16x8 o;
#pragma unroll
  for (int j = 0; j < 8; ++j) {
    int k = kb + j;
    float v = (k < DIM) ? Wl[k * DIM + c] : Wr[(k - DIM) * DIM + c];
    o[j] = (short)f2bf(v);
  }
  reinterpret_cast<bf16x8*>(Bpack)[(ks * 8 + nt) * 64 + lane] = o;
}

// ---------------------------------------------------------------------------
// K6: MFMA GEMM + fused bias/relu/row-masked column-sum -> per-wave partials
// ---------------------------------------------------------------------------
__global__ __launch_bounds__(256) void mfma_kernel(
    const short* __restrict__ A, const short* __restrict__ Bpack,
    const float* __restrict__ bl, float* __restrict__ partial, int nnodes) {
  __shared__ short a_lds[64 * 256];
  const int tid = threadIdx.x;
  const int wave = tid >> 6, lane = tid & 63;
  const int mt = blockIdx.x;
  const size_t abase = (size_t)mt * 64 * 256;

#pragma unroll
  for (int r = 0; r < 8; ++r) {
    int i = tid + 256 * r;
    int row = i >> 5, kc = i & 31;
    bf16x8 v = *reinterpret_cast<const bf16x8*>(A + abase + row * 256 + kc * 8);
    int byte = (row * 512 + kc * 16) ^ ((row & 7) << 4);
    *reinterpret_cast<bf16x8*>(reinterpret_cast<char*>(a_lds) + byte) = v;
  }
  __syncthreads();

  f32x4 acc[8];
#pragma unroll
  for (int nt = 0; nt < 8; ++nt) acc[nt] = (f32x4){0.f, 0.f, 0.f, 0.f};

  const int arow = wave * 16 + (lane & 15);
  const int kgrp = lane >> 4;
  const bf16x8* Bp = reinterpret_cast<const bf16x8*>(Bpack);

#pragma unroll
  for (int ks = 0; ks < 8; ++ks) {
    int byte = (arow * 512 + (ks * 32 + kgrp * 8) * 2) ^ ((arow & 7) << 4);
    bf16x8 a = *reinterpret_cast<const bf16x8*>(reinterpret_cast<char*>(a_lds) + byte);
#pragma unroll
    for (int nt = 0; nt < 8; ++nt) {
      bf16x8 b = Bp[(ks * 8 + nt) * 64 + lane];
      acc[nt] = __builtin_amdgcn_mfma_f32_16x16x32_bf16(a, b, acc[nt], 0, 0, 0);
    }
  }

  const int col16 = lane & 15;
  const int rowbase = mt * 64 + wave * 16 + kgrp * 4;
#pragma unroll
  for (int nt = 0; nt < 8; ++nt) {
    const int c = nt * 16 + col16;
    const float bb = bl[c];
    float s = 0.f;
#pragma unroll
    for (int rg = 0; rg < 4; ++rg) {
      float v = fmaxf(acc[nt][rg] + bb, 0.f);
      s += (rowbase + rg < nnodes) ? v : 0.f;
    }
    s += __shfl_xor(s, 16);
    s += __shfl_xor(s, 32);
    if (kgrp == 0) partial[((size_t)mt * 4 + wave) * DIM + c] = s;
  }
}

// ---------------------------------------------------------------------------
// K7a: parallel row-reduction of partial [nrows][128] -> red[128][128]
// ---------------------------------------------------------------------------
__global__ __launch_bounds__(256) void red1_kernel(
    const float* __restrict__ partial, int nrows, float* __restrict__ red) {
  __shared__ float tmp[128];
  const int c = threadIdx.x & 127;
  const int half = threadIdx.x >> 7;
  const int chunk = (nrows + 127) / 128;
  const int r0 = blockIdx.x * chunk;
  const int r1 = min(r0 + chunk, nrows);
  float s = 0.f;
  for (int r = r0 + half; r < r1; r += 2) s += partial[(size_t)r * DIM + c];
  if (half) tmp[c] = s;
  __syncthreads();
  if (!half) red[(size_t)blockIdx.x * DIM + c] = s + tmp[c];
}

// ---------------------------------------------------------------------------
// K7b: sum red's 128 rows, dot with W_out, scale, add bias.
// ---------------------------------------------------------------------------
__global__ __launch_bounds__(256) void red2_kernel(
    const float* __restrict__ red, const float* __restrict__ Wout,
    const float* __restrict__ bout, float* __restrict__ out, int nnodes) {
  __shared__ float tmp[128];
  __shared__ float prod[128];
  const int c = threadIdx.x & 127;
  const int half = threadIdx.x >> 7;
  float s = 0.f;
  for (int r = half; r < 128; r += 2) s += red[(size_t)r * DIM + c];
  if (half) tmp[c] = s;
  __syncthreads();
  if (!half) prod[c] = (s + tmp[c]) * Wout[c];
  __syncthreads();
  if (threadIdx.x == 0) {
    float v = 0.f;
    for (int i = 0; i < 128; ++i) v += prod[i];
    out[0] = v / (float)nnodes + bout[0];
  }
}

extern "C" void kernel_launch(void* const* d_in, const int* in_sizes, int n_in,
                              void* d_out, int out_size, void* d_ws, size_t ws_size,
                              hipStream_t stream) {
  const float* x    = (const float*)d_in[0];   // x_ligand [N,128]
  const int*   ei   = (const int*)d_in[4];     // ei_ll [2,E]
  const float* Wl   = (const float*)d_in[11];  // Wl_ll [128,128]
  const float* bl   = (const float*)d_in[12];  // bl_ll [128]
  const float* Wr   = (const float*)d_in[13];  // Wr_ll [128,128]
  const float* Wout = (const float*)d_in[14];  // W_out [128,1]
  const float* bout = (const float*)d_in[15];  // b_out [1]

  const int nnodes = in_sizes[0] / DIM;
  const int E = in_sizes[4] / 2;
  const int mtiles = (nnodes + 63) / 64;   // 782 == #regions
  const int mpad = mtiles * 64;            // 50048

  // ws layout: [rptr mtiles*8*RSTRIDE][cnt mpad][off mpad]
  //            [staging mtiles*REGCAP u32][A mpad*256 bf16][Bpack 32768 bf16]
  //            [red 128*128 f32]
  // partial (mtiles*4*128 f32 = 1.6MB) aliases staging (dead after agg).
  int*      rptr    = (int*)d_ws;
  int*      cnt     = rptr + (size_t)mtiles * NXCD * RSTRIDE;
  int*      off     = cnt + mpad;
  unsigned* staging = (unsigned*)(off + mpad);
  short*    A       = (short*)(staging + (size_t)mtiles * REGCAP);
  short*    Bpack   = A + (size_t)mpad * 256;
  float*    red     = (float*)(Bpack + 32768);
  float*    partial = (float*)staging;  // alias

  const int rptr_n4 = (mtiles * NXCD * RSTRIDE) / 4;  // 100096/4, divisible
  zero_kernel<<<(rptr_n4 + 255) / 256, 256, 0, stream>>>((int4v*)rptr, rptr_n4);

  partition_kernel<<<(E + 255) / 256, 256, 0, stream>>>(ei, rptr, staging, E);

  bpack_kernel<<<16, 256, 0, stream>>>(Wl, Wr, Bpack);

  xcast_kernel<<<(mpad * 32 + 255) / 256, 256, 0, stream>>>(x, A, nnodes, mpad);

  compact_kernel<<<mtiles, 256, 0, stream>>>(rptr, staging, cnt, off);

  agg_kernel<<<(mpad + 3) / 4, 256, 0, stream>>>(cnt, off, staging, A,
                                                 nnodes, mpad);

  mfma_kernel<<<mtiles, 256, 0, stream>>>(A, Bpack, bl, partial, nnodes);

  red1_kernel<<<128, 256, 0, stream>>>(partial, mtiles * 4, red);
  red2_kernel<<<1, 256, 0, stream>>>(red, Wout, bout, (float*)d_out, nnodes);
}

// Round 10
// 124.302 us; speedup vs baseline: 1.0350x; 1.0350x over previous
//
#include <hip/hip_runtime.h>
#include <hip/hip_bf16.h>

#define DIM 128
#define NXCD 8
#define SUBCAP 224              // per (region,xcd) capacity: mean 128 + 8.5 sigma
#define REGCAP (NXCD * SUBCAP)  // 1792 entries per region
#define RSTRIDE 16              // ints per counter (64B: one line per counter)

typedef __attribute__((ext_vector_type(8))) short bf16x8;
typedef __attribute__((ext_vector_type(4))) float f32x4;
typedef __attribute__((ext_vector_type(4))) short short4v;
typedef __attribute__((ext_vector_type(4))) int int4v;

__device__ inline unsigned short f2bf(float f) {
  union { float f; unsigned u; } v; v.f = f;
  return (unsigned short)((v.u + 0x7FFFu + ((v.u >> 16) & 1u)) >> 16);
}
__device__ inline float lo_f(unsigned u) {
  union { unsigned u; float f; } v; v.u = u << 16; return v.f;
}
__device__ inline float hi_f(unsigned u) {
  union { unsigned u; float f; } v; v.u = u & 0xFFFF0000u; return v.f;
}

// ---------------------------------------------------------------------------
// K0 "prep": fused zero(rptr) + bpack + xcast (disjoint outputs, one launch).
// Block roles by blockIdx.x: [0,xb) xcast | [xb,xb+16) bpack | rest zero.
// ---------------------------------------------------------------------------
__global__ __launch_bounds__(256) void prep_kernel(
    const float* __restrict__ x, short* __restrict__ A,
    const float* __restrict__ Wl, const float* __restrict__ Wr,
    short* __restrict__ Bpack, int* __restrict__ rptr,
    int nnodes, int mpad, int xb, int rptr_n4) {
  const int bid = blockIdx.x;
  if (bid < xb) {
    // xcast: cast x -> bf16 into x-half of A ([mpad][256] bf16, k>=128 = x)
    int t = bid * 256 + threadIdx.x;
    int node = t >> 5;
    if (node >= mpad) return;
    int c = (t & 31) * 4;
    short4v o = (short4v){0, 0, 0, 0};
    if (node < nnodes) {
      float4 v = *reinterpret_cast<const float4*>(x + (size_t)node * DIM + c);
      o.x = (short)f2bf(v.x); o.y = (short)f2bf(v.y);
      o.z = (short)f2bf(v.z); o.w = (short)f2bf(v.w);
    }
    *reinterpret_cast<short4v*>(A + (size_t)node * 256 + 128 + c) = o;
  } else if (bid < xb + 16) {
    // bpack: B = [[Wl];[Wr]] (256x128) into MFMA fragment order
    int t = (bid - xb) * 256 + threadIdx.x;
    if (t >= 4096) return;
    int lane = t & 63, nt = (t >> 6) & 7, ks = t >> 9;
    int c = nt * 16 + (lane & 15);
    int kb = ks * 32 + ((lane >> 4) << 3);
    bf16x8 o;
#pragma unroll
    for (int j = 0; j < 8; ++j) {
      int k = kb + j;
      float v = (k < DIM) ? Wl[k * DIM + c] : Wr[(k - DIM) * DIM + c];
      o[j] = (short)f2bf(v);
    }
    reinterpret_cast<bf16x8*>(Bpack)[(ks * 8 + nt) * 64 + lane] = o;
  } else {
    // zero rptr
    int i = (bid - xb - 16) * 256 + threadIdx.x;
    if (i < rptr_n4) reinterpret_cast<int4v*>(rptr)[i] = (int4v){0, 0, 0, 0};
  }
}

// ---------------------------------------------------------------------------
// K1: partition edges into 64-node dst-regions with XCD-LOCAL sub-lists.
// 4 edges/thread via int4 loads. blockIdx.x&7 proxies the XCD; each
// (region,xcd) sub-list's frontier lines stay in one XCD's L2 (one writeback).
// Entry = (dst&63)<<16 | src  (src < 65536 for N=50000).
// ---------------------------------------------------------------------------
__global__ __launch_bounds__(256) void partition_kernel(
    const int* __restrict__ ei, int* __restrict__ rptr,
    unsigned* __restrict__ staging, int E) {
  const int i = blockIdx.x * 256 + threadIdx.x;
  const int e0 = i * 4;
  if (e0 >= E) return;
  const int xcd = blockIdx.x & (NXCD - 1);
  int4 s4 = *reinterpret_cast<const int4*>(ei + e0);
  int4 d4 = *reinterpret_cast<const int4*>(ei + E + e0);
  const int ss[4] = {s4.x, s4.y, s4.z, s4.w};
  const int dd[4] = {d4.x, d4.y, d4.z, d4.w};
#pragma unroll
  for (int k = 0; k < 4; ++k) {
    if (e0 + k >= E) break;
    int r = dd[k] >> 6;
    int slot = atomicAdd(&rptr[(r * NXCD + xcd) * RSTRIDE], 1);
    if (slot < SUBCAP)
      staging[(size_t)r * REGCAP + xcd * SUBCAP + slot] =
          ((unsigned)(dd[k] & 63) << 16) | (unsigned)ss[k];
  }
}

// ---------------------------------------------------------------------------
// K2: per-region merge of 8 sub-lists + in-LDS counting sort -> dst-sorted
// src lists (in place, coalesced writeback) + per-node deg (cnt) and global
// offset (off). One block per region.
// ---------------------------------------------------------------------------
__global__ __launch_bounds__(256) void compact_kernel(
    const int* __restrict__ rptr, unsigned* __restrict__ staging,
    int* __restrict__ cnt, int* __restrict__ off) {
  __shared__ unsigned raw[REGCAP];
  __shared__ unsigned sorted[REGCAP];
  __shared__ int h[64];
  __shared__ int start[64];
  __shared__ int fill[64];
  __shared__ int scnt[NXCD];
  __shared__ int sub0[NXCD];
  const int region = blockIdx.x;
  const int tid = threadIdx.x;
  const size_t base = (size_t)region * REGCAP;

  if (tid < NXCD)
    scnt[tid] = min(rptr[(region * NXCD + tid) * RSTRIDE], SUBCAP);
  if (tid < 64) { h[tid] = 0; fill[tid] = 0; }
  __syncthreads();
  if (tid == 0) {
    int s = 0;
    for (int x = 0; x < NXCD; ++x) { sub0[x] = s; s += scnt[x]; }
  }
  __syncthreads();

  for (int x = 0; x < NXCD; ++x) {
    const int c = scnt[x];
    const int b = sub0[x];
    for (int i = tid; i < c; i += 256) {
      unsigned e = staging[base + x * SUBCAP + i];
      raw[b + i] = e;
      atomicAdd(&h[e >> 16], 1);
    }
  }
  __syncthreads();
  if (tid == 0) {
    int s = 0;
    for (int i = 0; i < 64; ++i) { start[i] = s; s += h[i]; }
  }
  __syncthreads();
  const int total = sub0[NXCD - 1] + scnt[NXCD - 1];
  for (int i = tid; i < total; i += 256) {
    unsigned e = raw[i];
    int d = (int)(e >> 16);
    int pos = start[d] + atomicAdd(&fill[d], 1);
    sorted[pos] = e & 0xFFFFu;  // keep only src
  }
  __syncthreads();
  for (int i = tid; i < total; i += 256) staging[base + i] = sorted[i];
  if (tid < 64) {
    int node = region * 64 + tid;
    cnt[node] = h[tid];
    off[node] = (int)base + start[tid];
  }
}

// ---------------------------------------------------------------------------
// K3: mean-aggregation, one wave per node (50048 waves of TLP). The node's
// src list is fetched with ONE coalesced wave load (ent = bucket[base+lane]),
// srcs broadcast via readlane -> gather rows 8-deep MLP (deg~16 -> 2 rounds).
// ---------------------------------------------------------------------------
__global__ __launch_bounds__(256) void agg_kernel(
    const int* __restrict__ cnt, const int* __restrict__ off,
    const unsigned* __restrict__ bucket, short* __restrict__ A,
    int nnodes, int mpad) {
  const int wid = (blockIdx.x * 256 + threadIdx.x) >> 6;
  const int lane = threadIdx.x & 63;
  if (wid >= mpad) return;
  unsigned* dst = reinterpret_cast<unsigned*>(A + (size_t)wid * 256) + lane;
  if (wid >= nnodes) { *dst = 0u; return; }
  const int deg  = __builtin_amdgcn_readfirstlane(cnt[wid]);
  const int base = __builtin_amdgcn_readfirstlane(off[wid]);
  const unsigned* xs = reinterpret_cast<const unsigned*>(A) + 64 + lane;

  // one coalesced load of the whole src list (deg <= 64 in practice)
  unsigned ent = (lane < deg) ? bucket[base + lane] : 0u;
  const int dcap = min(deg, 64);

  float l0 = 0.f, h0 = 0.f, l1 = 0.f, h1 = 0.f;
  int j = 0;
  for (; j + 7 < dcap; j += 8) {
    unsigned u[8];
#pragma unroll
    for (int k = 0; k < 8; ++k) {
      int s = __builtin_amdgcn_readlane((int)ent, j + k);
      u[k] = xs[(size_t)s * 128];
    }
#pragma unroll
    for (int k = 0; k < 8; ++k) {
      if (k & 1) { l1 += lo_f(u[k]); h1 += hi_f(u[k]); }
      else       { l0 += lo_f(u[k]); h0 += hi_f(u[k]); }
    }
  }
  for (; j < dcap; ++j) {
    int s = __builtin_amdgcn_readlane((int)ent, j);
    unsigned u0 = xs[(size_t)s * 128];
    l0 += lo_f(u0); h0 += hi_f(u0);
  }
  for (; j < deg; ++j) {  // astronomically-rare deg>64 tail
    int s = __builtin_amdgcn_readfirstlane((int)bucket[base + j]);
    unsigned u0 = xs[(size_t)s * 128];
    l0 += lo_f(u0); h0 += hi_f(u0);
  }
  const float r = 1.0f / fmaxf((float)deg, 1.0f);
  const float av = (l0 + l1) * r;
  const float bv = (h0 + h1) * r;
  *dst = (unsigned)f2bf(av) | ((unsigned)f2bf(bv) << 16);
}

// ---------------------------------------------------------------------------
// K4: MFMA GEMM + fused bias/relu/row-masked column-sum -> per-wave partials
// ---------------------------------------------------------------------------
__global__ __launch_bounds__(256) void mfma_kernel(
    const short* __restrict__ A, const short* __restrict__ Bpack,
    const float* __restrict__ bl, float* __restrict__ partial, int nnodes) {
  __shared__ short a_lds[64 * 256];
  const int tid = threadIdx.x;
  const int wave = tid >> 6, lane = tid & 63;
  const int mt = blockIdx.x;
  const size_t abase = (size_t)mt * 64 * 256;

#pragma unroll
  for (int r = 0; r < 8; ++r) {
    int i = tid + 256 * r;
    int row = i >> 5, kc = i & 31;
    bf16x8 v = *reinterpret_cast<const bf16x8*>(A + abase + row * 256 + kc * 8);
    int byte = (row * 512 + kc * 16) ^ ((row & 7) << 4);
    *reinterpret_cast<bf16x8*>(reinterpret_cast<char*>(a_lds) + byte) = v;
  }
  __syncthreads();

  f32x4 acc[8];
#pragma unroll
  for (int nt = 0; nt < 8; ++nt) acc[nt] = (f32x4){0.f, 0.f, 0.f, 0.f};

  const int arow = wave * 16 + (lane & 15);
  const int kgrp = lane >> 4;
  const bf16x8* Bp = reinterpret_cast<const bf16x8*>(Bpack);

#pragma unroll
  for (int ks = 0; ks < 8; ++ks) {
    int byte = (arow * 512 + (ks * 32 + kgrp * 8) * 2) ^ ((arow & 7) << 4);
    bf16x8 a = *reinterpret_cast<const bf16x8*>(reinterpret_cast<char*>(a_lds) + byte);
#pragma unroll
    for (int nt = 0; nt < 8; ++nt) {
      bf16x8 b = Bp[(ks * 8 + nt) * 64 + lane];
      acc[nt] = __builtin_amdgcn_mfma_f32_16x16x32_bf16(a, b, acc[nt], 0, 0, 0);
    }
  }

  const int col16 = lane & 15;
  const int rowbase = mt * 64 + wave * 16 + kgrp * 4;
#pragma unroll
  for (int nt = 0; nt < 8; ++nt) {
    const int c = nt * 16 + col16;
    const float bb = bl[c];
    float s = 0.f;
#pragma unroll
    for (int rg = 0; rg < 4; ++rg) {
      float v = fmaxf(acc[nt][rg] + bb, 0.f);
      s += (rowbase + rg < nnodes) ? v : 0.f;
    }
    s += __shfl_xor(s, 16);
    s += __shfl_xor(s, 32);
    if (kgrp == 0) partial[((size_t)mt * 4 + wave) * DIM + c] = s;
  }
}

// ---------------------------------------------------------------------------
// K5a: parallel row-reduction of partial [nrows][128] -> red[128][128]
// ---------------------------------------------------------------------------
__global__ __launch_bounds__(256) void red1_kernel(
    const float* __restrict__ partial, int nrows, float* __restrict__ red) {
  __shared__ float tmp[128];
  const int c = threadIdx.x & 127;
  const int half = threadIdx.x >> 7;
  const int chunk = (nrows + 127) / 128;
  const int r0 = blockIdx.x * chunk;
  const int r1 = min(r0 + chunk, nrows);
  float s = 0.f;
  for (int r = r0 + half; r < r1; r += 2) s += partial[(size_t)r * DIM + c];
  if (half) tmp[c] = s;
  __syncthreads();
  if (!half) red[(size_t)blockIdx.x * DIM + c] = s + tmp[c];
}

// ---------------------------------------------------------------------------
// K5b: sum red's 128 rows, dot with W_out, scale, add bias.
// ---------------------------------------------------------------------------
__global__ __launch_bounds__(256) void red2_kernel(
    const float* __restrict__ red, const float* __restrict__ Wout,
    const float* __restrict__ bout, float* __restrict__ out, int nnodes) {
  __shared__ float tmp[128];
  __shared__ float prod[128];
  const int c = threadIdx.x & 127;
  const int half = threadIdx.x >> 7;
  float s = 0.f;
  for (int r = half; r < 128; r += 2) s += red[(size_t)r * DIM + c];
  if (half) tmp[c] = s;
  __syncthreads();
  if (!half) prod[c] = (s + tmp[c]) * Wout[c];
  __syncthreads();
  if (threadIdx.x == 0) {
    float v = 0.f;
    for (int i = 0; i < 128; ++i) v += prod[i];
    out[0] = v / (float)nnodes + bout[0];
  }
}

extern "C" void kernel_launch(void* const* d_in, const int* in_sizes, int n_in,
                              void* d_out, int out_size, void* d_ws, size_t ws_size,
                              hipStream_t stream) {
  const float* x    = (const float*)d_in[0];   // x_ligand [N,128]
  const int*   ei   = (const int*)d_in[4];     // ei_ll [2,E]
  const float* Wl   = (const float*)d_in[11];  // Wl_ll [128,128]
  const float* bl   = (const float*)d_in[12];  // bl_ll [128]
  const float* Wr   = (const float*)d_in[13];  // Wr_ll [128,128]
  const float* Wout = (const float*)d_in[14];  // W_out [128,1]
  const float* bout = (const float*)d_in[15];  // b_out [1]

  const int nnodes = in_sizes[0] / DIM;
  const int E = in_sizes[4] / 2;
  const int mtiles = (nnodes + 63) / 64;   // 782 == #regions
  const int mpad = mtiles * 64;            // 50048

  // ws layout: [rptr mtiles*8*RSTRIDE][cnt mpad][off mpad]
  //            [staging mtiles*REGCAP u32][A mpad*256 bf16][Bpack 32768 bf16]
  //            [red 128*128 f32]
  // partial (mtiles*4*128 f32 = 1.6MB) aliases staging (dead after agg).
  int*      rptr    = (int*)d_ws;
  int*      cnt     = rptr + (size_t)mtiles * NXCD * RSTRIDE;
  int*      off     = cnt + mpad;
  unsigned* staging = (unsigned*)(off + mpad);
  short*    A       = (short*)(staging + (size_t)mtiles * REGCAP);
  short*    Bpack   = A + (size_t)mpad * 256;
  float*    red     = (float*)(Bpack + 32768);
  float*    partial = (float*)staging;  // alias

  const int rptr_n4 = (mtiles * NXCD * RSTRIDE) / 4;
  const int xb = mpad / 8;                         // xcast blocks (mpad*32/256)
  const int zb = (rptr_n4 + 255) / 256;            // zero blocks
  prep_kernel<<<xb + 16 + zb, 256, 0, stream>>>(x, A, Wl, Wr, Bpack, rptr,
                                                nnodes, mpad, xb, rptr_n4);

  partition_kernel<<<(E / 4 + 255) / 256, 256, 0, stream>>>(ei, rptr, staging, E);

  compact_kernel<<<mtiles, 256, 0, stream>>>(rptr, staging, cnt, off);

  agg_kernel<<<(mpad + 3) / 4, 256, 0, stream>>>(cnt, off, staging, A,
                                                 nnodes, mpad);

  mfma_kernel<<<mtiles, 256, 0, stream>>>(A, Bpack, bl, partial, nnodes);

  red1_kernel<<<128, 256, 0, stream>>>(partial, mtiles * 4, red);
  red2_kernel<<<1, 256, 0, stream>>>(red, Wout, bout, (float*)d_out, nnodes);
}

// Round 11
// 123.842 us; speedup vs baseline: 1.0388x; 1.0037x over previous
//
#include <hip/hip_runtime.h>
#include <hip/hip_bf16.h>

#define DIM 128
#define NXCD 8
#define SUBCAP 288              // per (region,xcd) capacity: 2.25x mean of 128
#define REGCAP (NXCD * SUBCAP)  // 2304 entries per region
#define RSTRIDE 16              // ints per counter (64B: one line per counter)

typedef __attribute__((ext_vector_type(8))) short bf16x8;
typedef __attribute__((ext_vector_type(4))) float f32x4;
typedef __attribute__((ext_vector_type(4))) short short4v;
typedef __attribute__((ext_vector_type(4))) int int4v;

__device__ inline unsigned short f2bf(float f) {
  union { float f; unsigned u; } v; v.f = f;
  return (unsigned short)((v.u + 0x7FFFu + ((v.u >> 16) & 1u)) >> 16);
}
__device__ inline float lo_f(unsigned u) {
  union { unsigned u; float f; } v; v.u = u << 16; return v.f;
}
__device__ inline float hi_f(unsigned u) {
  union { unsigned u; float f; } v; v.u = u & 0xFFFF0000u; return v.f;
}

// ---------------------------------------------------------------------------
// K0 "prep": fused zero(rptr) + bpack + xcast (disjoint outputs, one launch).
// Block roles by blockIdx.x: [0,xb) xcast | [xb,xb+16) bpack | rest zero.
// ---------------------------------------------------------------------------
__global__ __launch_bounds__(256) void prep_kernel(
    const float* __restrict__ x, short* __restrict__ A,
    const float* __restrict__ Wl, const float* __restrict__ Wr,
    short* __restrict__ Bpack, int* __restrict__ rptr,
    int nnodes, int mpad, int xb, int rptr_n4) {
  const int bid = blockIdx.x;
  if (bid < xb) {
    // xcast: cast x -> bf16 into x-half of A ([mpad][256] bf16, k>=128 = x)
    int t = bid * 256 + threadIdx.x;
    int node = t >> 5;
    if (node >= mpad) return;
    int c = (t & 31) * 4;
    short4v o = (short4v){0, 0, 0, 0};
    if (node < nnodes) {
      float4 v = *reinterpret_cast<const float4*>(x + (size_t)node * DIM + c);
      o.x = (short)f2bf(v.x); o.y = (short)f2bf(v.y);
      o.z = (short)f2bf(v.z); o.w = (short)f2bf(v.w);
    }
    *reinterpret_cast<short4v*>(A + (size_t)node * 256 + 128 + c) = o;
  } else if (bid < xb + 16) {
    // bpack: B = [[Wl];[Wr]] (256x128) into MFMA fragment order
    int t = (bid - xb) * 256 + threadIdx.x;
    if (t >= 4096) return;
    int lane = t & 63, nt = (t >> 6) & 7, ks = t >> 9;
    int c = nt * 16 + (lane & 15);
    int kb = ks * 32 + ((lane >> 4) << 3);
    bf16x8 o;
#pragma unroll
    for (int j = 0; j < 8; ++j) {
      int k = kb + j;
      float v = (k < DIM) ? Wl[k * DIM + c] : Wr[(k - DIM) * DIM + c];
      o[j] = (short)f2bf(v);
    }
    reinterpret_cast<bf16x8*>(Bpack)[(ks * 8 + nt) * 64 + lane] = o;
  } else {
    // zero rptr
    int i = (bid - xb - 16) * 256 + threadIdx.x;
    if (i < rptr_n4) reinterpret_cast<int4v*>(rptr)[i] = (int4v){0, 0, 0, 0};
  }
}

// ---------------------------------------------------------------------------
// K1: partition edges into 64-node dst-regions with XCD-LOCAL sub-lists,
// keyed by the TRUE XCD id (s_getreg HW_REG_XCC_ID — blockIdx&7 was a wrong
// proxy: round-10 PMC showed 28MB partial-line writebacks from cross-XCD
// dirty copies). Each (region,xcd) sub-list + counter is touched by exactly
// one L2 -> lines written back once, full. Entry = (dst&63)<<16 | src.
// ---------------------------------------------------------------------------
__global__ __launch_bounds__(256) void partition_kernel(
    const int* __restrict__ ei, int* __restrict__ rptr,
    unsigned* __restrict__ staging, int E) {
  const int i = blockIdx.x * 256 + threadIdx.x;
  const int e0 = i * 4;
  if (e0 >= E) return;
  unsigned xcc;
  asm volatile("s_getreg_b32 %0, hwreg(HW_REG_XCC_ID)" : "=s"(xcc));
  const int xcd = (int)(xcc & (NXCD - 1));
  int4 s4 = *reinterpret_cast<const int4*>(ei + e0);
  int4 d4 = *reinterpret_cast<const int4*>(ei + E + e0);
  const int ss[4] = {s4.x, s4.y, s4.z, s4.w};
  const int dd[4] = {d4.x, d4.y, d4.z, d4.w};
#pragma unroll
  for (int k = 0; k < 4; ++k) {
    if (e0 + k >= E) break;
    int r = dd[k] >> 6;
    int slot = atomicAdd(&rptr[(r * NXCD + xcd) * RSTRIDE], 1);
    if (slot < SUBCAP)
      staging[(size_t)r * REGCAP + xcd * SUBCAP + slot] =
          ((unsigned)(dd[k] & 63) << 16) | (unsigned)ss[k];
  }
}

// ---------------------------------------------------------------------------
// K2: per-region merge of 8 sub-lists + in-LDS counting sort -> dst-sorted
// src lists (in place, coalesced writeback) + per-node deg (cnt) and global
// offset (off). One block per region.
// ---------------------------------------------------------------------------
__global__ __launch_bounds__(256) void compact_kernel(
    const int* __restrict__ rptr, unsigned* __restrict__ staging,
    int* __restrict__ cnt, int* __restrict__ off) {
  __shared__ unsigned raw[REGCAP];
  __shared__ unsigned sorted[REGCAP];
  __shared__ int h[64];
  __shared__ int start[64];
  __shared__ int fill[64];
  __shared__ int scnt[NXCD];
  __shared__ int sub0[NXCD];
  const int region = blockIdx.x;
  const int tid = threadIdx.x;
  const size_t base = (size_t)region * REGCAP;

  if (tid < NXCD)
    scnt[tid] = min(rptr[(region * NXCD + tid) * RSTRIDE], SUBCAP);
  if (tid < 64) { h[tid] = 0; fill[tid] = 0; }
  __syncthreads();
  if (tid == 0) {
    int s = 0;
    for (int x = 0; x < NXCD; ++x) { sub0[x] = s; s += scnt[x]; }
  }
  __syncthreads();

  for (int x = 0; x < NXCD; ++x) {
    const int c = scnt[x];
    const int b = sub0[x];
    for (int i = tid; i < c; i += 256) {
      unsigned e = staging[base + x * SUBCAP + i];
      raw[b + i] = e;
      atomicAdd(&h[e >> 16], 1);
    }
  }
  __syncthreads();
  if (tid == 0) {
    int s = 0;
    for (int i = 0; i < 64; ++i) { start[i] = s; s += h[i]; }
  }
  __syncthreads();
  const int total = sub0[NXCD - 1] + scnt[NXCD - 1];
  for (int i = tid; i < total; i += 256) {
    unsigned e = raw[i];
    int d = (int)(e >> 16);
    int pos = start[d] + atomicAdd(&fill[d], 1);
    sorted[pos] = e & 0xFFFFu;  // keep only src
  }
  __syncthreads();
  for (int i = tid; i < total; i += 256) staging[base + i] = sorted[i];
  if (tid < 64) {
    int node = region * 64 + tid;
    cnt[node] = h[tid];
    off[node] = (int)base + start[tid];
  }
}

// ---------------------------------------------------------------------------
// K3: mean-aggregation, one wave per node (50048 waves of TLP). The node's
// src list is fetched with ONE coalesced wave load (ent = bucket[base+lane]),
// srcs broadcast via readlane -> gather rows 8-deep MLP (deg~16 -> 2 rounds).
// ---------------------------------------------------------------------------
__global__ __launch_bounds__(256) void agg_kernel(
    const int* __restrict__ cnt, const int* __restrict__ off,
    const unsigned* __restrict__ bucket, short* __restrict__ A,
    int nnodes, int mpad) {
  const int wid = (blockIdx.x * 256 + threadIdx.x) >> 6;
  const int lane = threadIdx.x & 63;
  if (wid >= mpad) return;
  unsigned* dst = reinterpret_cast<unsigned*>(A + (size_t)wid * 256) + lane;
  if (wid >= nnodes) { *dst = 0u; return; }
  const int deg  = __builtin_amdgcn_readfirstlane(cnt[wid]);
  const int base = __builtin_amdgcn_readfirstlane(off[wid]);
  const unsigned* xs = reinterpret_cast<const unsigned*>(A) + 64 + lane;

  // one coalesced load of the whole src list (deg <= 64 in practice)
  unsigned ent = (lane < deg) ? bucket[base + lane] : 0u;
  const int dcap = min(deg, 64);

  float l0 = 0.f, h0 = 0.f, l1 = 0.f, h1 = 0.f;
  int j = 0;
  for (; j + 7 < dcap; j += 8) {
    unsigned u[8];
#pragma unroll
    for (int k = 0; k < 8; ++k) {
      int s = __builtin_amdgcn_readlane((int)ent, j + k);
      u[k] = xs[(size_t)s * 128];
    }
#pragma unroll
    for (int k = 0; k < 8; ++k) {
      if (k & 1) { l1 += lo_f(u[k]); h1 += hi_f(u[k]); }
      else       { l0 += lo_f(u[k]); h0 += hi_f(u[k]); }
    }
  }
  for (; j < dcap; ++j) {
    int s = __builtin_amdgcn_readlane((int)ent, j);
    unsigned u0 = xs[(size_t)s * 128];
    l0 += lo_f(u0); h0 += hi_f(u0);
  }
  for (; j < deg; ++j) {  // astronomically-rare deg>64 tail
    int s = __builtin_amdgcn_readfirstlane((int)bucket[base + j]);
    unsigned u0 = xs[(size_t)s * 128];
    l0 += lo_f(u0); h0 += hi_f(u0);
  }
  const float r = 1.0f / fmaxf((float)deg, 1.0f);
  const float av = (l0 + l1) * r;
  const float bv = (h0 + h1) * r;
  *dst = (unsigned)f2bf(av) | ((unsigned)f2bf(bv) << 16);
}

// ---------------------------------------------------------------------------
// K4: MFMA GEMM + fused bias/relu/row-masked column-sum -> per-wave partials
// ---------------------------------------------------------------------------
__global__ __launch_bounds__(256) void mfma_kernel(
    const short* __restrict__ A, const short* __restrict__ Bpack,
    const float* __restrict__ bl, float* __restrict__ partial, int nnodes) {
  __shared__ short a_lds[64 * 256];
  const int tid = threadIdx.x;
  const int wave = tid >> 6, lane = tid & 63;
  const int mt = blockIdx.x;
  const size_t abase = (size_t)mt * 64 * 256;

#pragma unroll
  for (int r = 0; r < 8; ++r) {
    int i = tid + 256 * r;
    int row = i >> 5, kc = i & 31;
    bf16x8 v = *reinterpret_cast<const bf16x8*>(A + abase + row * 256 + kc * 8);
    int byte = (row * 512 + kc * 16) ^ ((row & 7) << 4);
    *reinterpret_cast<bf16x8*>(reinterpret_cast<char*>(a_lds) + byte) = v;
  }
  __syncthreads();

  f32x4 acc[8];
#pragma unroll
  for (int nt = 0; nt < 8; ++nt) acc[nt] = (f32x4){0.f, 0.f, 0.f, 0.f};

  const int arow = wave * 16 + (lane & 15);
  const int kgrp = lane >> 4;
  const bf16x8* Bp = reinterpret_cast<const bf16x8*>(Bpack);

#pragma unroll
  for (int ks = 0; ks < 8; ++ks) {
    int byte = (arow * 512 + (ks * 32 + kgrp * 8) * 2) ^ ((arow & 7) << 4);
    bf16x8 a = *reinterpret_cast<const bf16x8*>(reinterpret_cast<char*>(a_lds) + byte);
#pragma unroll
    for (int nt = 0; nt < 8; ++nt) {
      bf16x8 b = Bp[(ks * 8 + nt) * 64 + lane];
      acc[nt] = __builtin_amdgcn_mfma_f32_16x16x32_bf16(a, b, acc[nt], 0, 0, 0);
    }
  }

  const int col16 = lane & 15;
  const int rowbase = mt * 64 + wave * 16 + kgrp * 4;
#pragma unroll
  for (int nt = 0; nt < 8; ++nt) {
    const int c = nt * 16 + col16;
    const float bb = bl[c];
    float s = 0.f;
#pragma unroll
    for (int rg = 0; rg < 4; ++rg) {
      float v = fmaxf(acc[nt][rg] + bb, 0.f);
      s += (rowbase + rg < nnodes) ? v : 0.f;
    }
    s += __shfl_xor(s, 16);
    s += __shfl_xor(s, 32);
    if (kgrp == 0) partial[((size_t)mt * 4 + wave) * DIM + c] = s;
  }
}

// ---------------------------------------------------------------------------
// K5a: parallel row-reduction of partial [nrows][128] -> red[128][128]
// ---------------------------------------------------------------------------
__global__ __launch_bounds__(256) void red1_kernel(
    const float* __restrict__ partial, int nrows, float* __restrict__ red) {
  __shared__ float tmp[128];
  const int c = threadIdx.x & 127;
  const int half = threadIdx.x >> 7;
  const int chunk = (nrows + 127) / 128;
  const int r0 = blockIdx.x * chunk;
  const int r1 = min(r0 + chunk, nrows);
  float s = 0.f;
  for (int r = r0 + half; r < r1; r += 2) s += partial[(size_t)r * DIM + c];
  if (half) tmp[c] = s;
  __syncthreads();
  if (!half) red[(size_t)blockIdx.x * DIM + c] = s + tmp[c];
}

// ---------------------------------------------------------------------------
// K5b: sum red's 128 rows, dot with W_out, scale, add bias.
// ---------------------------------------------------------------------------
__global__ __launch_bounds__(256) void red2_kernel(
    const float* __restrict__ red, const float* __restrict__ Wout,
    const float* __restrict__ bout, float* __restrict__ out, int nnodes) {
  __shared__ float tmp[128];
  __shared__ float prod[128];
  const int c = threadIdx.x & 127;
  const int half = threadIdx.x >> 7;
  float s = 0.f;
  for (int r = half; r < 128; r += 2) s += red[(size_t)r * DIM + c];
  if (half) tmp[c] = s;
  __syncthreads();
  if (!half) prod[c] = (s + tmp[c]) * Wout[c];
  __syncthreads();
  if (threadIdx.x == 0) {
    float v = 0.f;
    for (int i = 0; i < 128; ++i) v += prod[i];
    out[0] = v / (float)nnodes + bout[0];
  }
}

extern "C" void kernel_launch(void* const* d_in, const int* in_sizes, int n_in,
                              void* d_out, int out_size, void* d_ws, size_t ws_size,
                              hipStream_t stream) {
  const float* x    = (const float*)d_in[0];   // x_ligand [N,128]
  const int*   ei   = (const int*)d_in[4];     // ei_ll [2,E]
  const float* Wl   = (const float*)d_in[11];  // Wl_ll [128,128]
  const float* bl   = (const float*)d_in[12];  // bl_ll [128]
  const float* Wr   = (const float*)d_in[13];  // Wr_ll [128,128]
  const float* Wout = (const float*)d_in[14];  // W_out [128,1]
  const float* bout = (const float*)d_in[15];  // b_out [1]

  const int nnodes = in_sizes[0] / DIM;
  const int E = in_sizes[4] / 2;
  const int mtiles = (nnodes + 63) / 64;   // 782 == #regions
  const int mpad = mtiles * 64;            // 50048

  // ws layout: [rptr mtiles*8*RSTRIDE][cnt mpad][off mpad]
  //            [staging mtiles*REGCAP u32][A mpad*256 bf16][Bpack 32768 bf16]
  //            [red 128*128 f32]
  // partial (mtiles*4*128 f32 = 1.6MB) aliases staging (dead after agg).
  int*      rptr    = (int*)d_ws;
  int*      cnt     = rptr + (size_t)mtiles * NXCD * RSTRIDE;
  int*      off     = cnt + mpad;
  unsigned* staging = (unsigned*)(off + mpad);
  short*    A       = (short*)(staging + (size_t)mtiles * REGCAP);
  short*    Bpack   = A + (size_t)mpad * 256;
  float*    red     = (float*)(Bpack + 32768);
  float*    partial = (float*)staging;  // alias

  const int rptr_n4 = (mtiles * NXCD * RSTRIDE) / 4;
  const int xb = mpad / 8;                         // xcast blocks (mpad*32/256)
  const int zb = (rptr_n4 + 255) / 256;            // zero blocks
  prep_kernel<<<xb + 16 + zb, 256, 0, stream>>>(x, A, Wl, Wr, Bpack, rptr,
                                                nnodes, mpad, xb, rptr_n4);

  partition_kernel<<<(E / 4 + 255) / 256, 256, 0, stream>>>(ei, rptr, staging, E);

  compact_kernel<<<mtiles, 256, 0, stream>>>(rptr, staging, cnt, off);

  agg_kernel<<<(mpad + 3) / 4, 256, 0, stream>>>(cnt, off, staging, A,
                                                 nnodes, mpad);

  mfma_kernel<<<mtiles, 256, 0, stream>>>(A, Bpack, bl, partial, nnodes);

  red1_kernel<<<128, 256, 0, stream>>>(partial, mtiles * 4, red);
  red2_kernel<<<1, 256, 0, stream>>>(red, Wout, bout, (float*)d_out, nnodes);
}

// Round 12
// 95.154 us; speedup vs baseline: 1.3520x; 1.3015x over previous
//
#include <hip/hip_runtime.h>
#include <hip/hip_bf16.h>

#define DIM 128
#define EPB 4096     // edges per partition chunk/block
#define NRBIN 1024   // region bins (mtiles=782 padded to pow2; 10 bits)
#define RCAP 1280    // final per-region CSR capacity (mean 1023 + 8 sigma)

typedef __attribute__((ext_vector_type(8))) short bf16x8;
typedef __attribute__((ext_vector_type(4))) float f32x4;
typedef __attribute__((ext_vector_type(4))) short short4v;
typedef __attribute__((ext_vector_type(4))) int int4v;

__device__ inline unsigned short f2bf(float f) {
  union { float f; unsigned u; } v; v.f = f;
  return (unsigned short)((v.u + 0x7FFFu + ((v.u >> 16) & 1u)) >> 16);
}
__device__ inline float lo_f(unsigned u) {
  union { unsigned u; float f; } v; v.u = u << 16; return v.f;
}
__device__ inline float hi_f(unsigned u) {
  union { unsigned u; float f; } v; v.u = u & 0xFFFF0000u; return v.f;
}

// ---------------------------------------------------------------------------
// K0 "prep": fused bpack + xcast (disjoint outputs, one launch).
// ---------------------------------------------------------------------------
__global__ __launch_bounds__(256) void prep_kernel(
    const float* __restrict__ x, short* __restrict__ A,
    const float* __restrict__ Wl, const float* __restrict__ Wr,
    short* __restrict__ Bpack, int nnodes, int mpad, int xb) {
  const int bid = blockIdx.x;
  if (bid < xb) {
    int t = bid * 256 + threadIdx.x;
    int node = t >> 5;
    if (node >= mpad) return;
    int c = (t & 31) * 4;
    short4v o = (short4v){0, 0, 0, 0};
    if (node < nnodes) {
      float4 v = *reinterpret_cast<const float4*>(x + (size_t)node * DIM + c);
      o.x = (short)f2bf(v.x); o.y = (short)f2bf(v.y);
      o.z = (short)f2bf(v.z); o.w = (short)f2bf(v.w);
    }
    *reinterpret_cast<short4v*>(A + (size_t)node * 256 + 128 + c) = o;
  } else {
    int t = (bid - xb) * 256 + threadIdx.x;
    if (t >= 4096) return;
    int lane = t & 63, nt = (t >> 6) & 7, ks = t >> 9;
    int c = nt * 16 + (lane & 15);
    int kb = ks * 32 + ((lane >> 4) << 3);
    bf16x8 o;
#pragma unroll
    for (int j = 0; j < 8; ++j) {
      int k = kb + j;
      float v = (k < DIM) ? Wl[k * DIM + c] : Wr[(k - DIM) * DIM + c];
      o[j] = (short)f2bf(v);
    }
    reinterpret_cast<bf16x8*>(Bpack)[(ks * 8 + nt) * 64 + lane] = o;
  }
}

// ---------------------------------------------------------------------------
// K1: atomic-free partition. One block per 4096-edge chunk: in-LDS counting
// sort by region (entry = region<<22 | (dst&63)<<16 | src), then DENSE
// coalesced writeback of the sorted chunk + per-chunk starts/counts rows.
// (Round-11 PMC: 28MB WRITE was ~32B write-through per global atomicAdd —
// this kernel has ZERO global atomics and only full-line stores.)
// ---------------------------------------------------------------------------
__global__ __launch_bounds__(256) void partition_kernel(
    const int* __restrict__ ei, unsigned* __restrict__ chunkbuf,
    int* __restrict__ startsT, int* __restrict__ countsT, int E) {
  __shared__ unsigned uns[EPB];
  __shared__ unsigned srt[EPB];
  __shared__ int lhist[NRBIN];
  __shared__ int lstart[NRBIN];
  __shared__ int tsum[256];
  const int tid = threadIdx.x;
  const int chunk = blockIdx.x;
  const int base = chunk * EPB;
  const int count = min(EPB, E - base);

#pragma unroll
  for (int r = 0; r < NRBIN / 256; ++r) lhist[tid + 256 * r] = 0;
  __syncthreads();

  // phase A: load edges, pack entries, LDS histogram by region
  for (int r = 0; r < EPB / 1024; ++r) {
    int i = r * 1024 + tid * 4;
    if (i + 3 < count) {
      int4 s4 = *reinterpret_cast<const int4*>(ei + base + i);
      int4 d4 = *reinterpret_cast<const int4*>(ei + E + base + i);
      int ss[4] = {s4.x, s4.y, s4.z, s4.w};
      int dd[4] = {d4.x, d4.y, d4.z, d4.w};
#pragma unroll
      for (int k = 0; k < 4; ++k) {
        unsigned reg = (unsigned)dd[k] >> 6;
        uns[i + k] = (reg << 22) | ((unsigned)(dd[k] & 63) << 16) | (unsigned)ss[k];
        atomicAdd(&lhist[reg], 1);
      }
    } else {
      for (int k = 0; k < 4; ++k) {
        if (i + k < count) {
          int s = ei[base + i + k], d = ei[E + base + i + k];
          unsigned reg = (unsigned)d >> 6;
          uns[i + k] = (reg << 22) | ((unsigned)(d & 63) << 16) | (unsigned)s;
          atomicAdd(&lhist[reg], 1);
        }
      }
    }
  }
  __syncthreads();

  // exclusive scan of lhist (4 bins/thread + block scan of thread sums)
  int h0 = lhist[tid * 4], h1 = lhist[tid * 4 + 1];
  int h2 = lhist[tid * 4 + 2], h3 = lhist[tid * 4 + 3];
  int local = h0 + h1 + h2 + h3;
  tsum[tid] = local;
  __syncthreads();
  for (int o = 1; o < 256; o <<= 1) {
    int t = (tid >= o) ? tsum[tid - o] : 0;
    __syncthreads();
    tsum[tid] += t;
    __syncthreads();
  }
  int tb = tsum[tid] - local;
  lstart[tid * 4]     = tb;
  lstart[tid * 4 + 1] = tb + h0;
  lstart[tid * 4 + 2] = tb + h0 + h1;
  lstart[tid * 4 + 3] = tb + h0 + h1 + h2;
  lhist[tid * 4] = 0; lhist[tid * 4 + 1] = 0;
  lhist[tid * 4 + 2] = 0; lhist[tid * 4 + 3] = 0;  // becomes fill counter
  __syncthreads();

  // phase B: scatter into region-sorted LDS order
  for (int i = tid; i < count; i += 256) {
    unsigned e = uns[i];
    unsigned reg = e >> 22;
    int pos = lstart[reg] + atomicAdd(&lhist[reg], 1);
    srt[pos] = e;
  }
  __syncthreads();

  // dense writeback: sorted chunk (int4) + starts/counts rows
  for (int r = 0; r < EPB / 1024; ++r) {
    int i = r * 1024 + tid * 4;
    if (i + 3 < count) {
      int4v v = {(int)srt[i], (int)srt[i + 1], (int)srt[i + 2], (int)srt[i + 3]};
      *reinterpret_cast<int4v*>(chunkbuf + (size_t)chunk * EPB + i) = v;
    } else {
      for (int k = 0; k < 4; ++k)
        if (i + k < count) chunkbuf[(size_t)chunk * EPB + i + k] = srt[i + k];
    }
  }
  for (int r = tid; r < NRBIN; r += 256) {
    startsT[(size_t)chunk * NRBIN + r] = lstart[r];
    countsT[(size_t)chunk * NRBIN + r] = lhist[r];  // == per-region count again
  }
}

// ---------------------------------------------------------------------------
// K2: per-region merge of per-chunk runs (one chunk per thread, prefix via
// LDS scan) + node-level counting sort -> final CSR + cnt/off. No atomics
// outside LDS. Assumes nchunk <= 256 (196 for E=800K).
// ---------------------------------------------------------------------------
__global__ __launch_bounds__(256) void compact_kernel(
    const unsigned* __restrict__ chunkbuf, const int* __restrict__ startsT,
    const int* __restrict__ countsT, int nchunk, unsigned* __restrict__ csr,
    int* __restrict__ cnt, int* __restrict__ off) {
  __shared__ unsigned raw[RCAP];
  __shared__ unsigned srt[RCAP];
  __shared__ int h[64];
  __shared__ int start[64];
  __shared__ int tsum[256];
  const int region = blockIdx.x;
  const int tid = threadIdx.x;

  int cn = 0, st = 0;
  if (tid < nchunk) {
    cn = countsT[(size_t)tid * NRBIN + region];
    st = startsT[(size_t)tid * NRBIN + region];
  }
  tsum[tid] = cn;
  __syncthreads();
  for (int o = 1; o < 256; o <<= 1) {
    int t = (tid >= o) ? tsum[tid - o] : 0;
    __syncthreads();
    tsum[tid] += t;
    __syncthreads();
  }
  const int pfx = tsum[tid] - cn;
  int total = min(tsum[255], RCAP);

  const unsigned* src = chunkbuf + (size_t)tid * EPB + st;
  for (int j = 0; j < cn && pfx + j < RCAP; ++j) raw[pfx + j] = src[j];
  if (tid < 64) h[tid] = 0;
  __syncthreads();

  for (int i = tid; i < total; i += 256) atomicAdd(&h[(raw[i] >> 16) & 63], 1);
  __syncthreads();
  if (tid == 0) {
    int s = 0;
    for (int i = 0; i < 64; ++i) { start[i] = s; s += h[i]; }
  }
  __syncthreads();
  if (tid < 64) {
    int node = region * 64 + tid;
    cnt[node] = h[tid];
    off[node] = region * RCAP + start[tid];
    h[tid] = 0;  // becomes fill counter
  }
  __syncthreads();
  for (int i = tid; i < total; i += 256) {
    unsigned e = raw[i];
    int d = (e >> 16) & 63;
    int pos = start[d] + atomicAdd(&h[d], 1);
    srt[pos] = e & 0xFFFFu;  // keep only src
  }
  __syncthreads();
  for (int i = tid; i < total; i += 256) csr[(size_t)region * RCAP + i] = srt[i];
}

// ---------------------------------------------------------------------------
// K3: mean-aggregation, one wave per node (50048 waves of TLP). Src list via
// ONE coalesced wave load + readlane broadcast; 8-deep row-gather MLP.
// ---------------------------------------------------------------------------
__global__ __launch_bounds__(256) void agg_kernel(
    const int* __restrict__ cnt, const int* __restrict__ off,
    const unsigned* __restrict__ bucket, short* __restrict__ A,
    int nnodes, int mpad) {
  const int wid = (blockIdx.x * 256 + threadIdx.x) >> 6;
  const int lane = threadIdx.x & 63;
  if (wid >= mpad) return;
  unsigned* dst = reinterpret_cast<unsigned*>(A + (size_t)wid * 256) + lane;
  if (wid >= nnodes) { *dst = 0u; return; }
  const int deg  = __builtin_amdgcn_readfirstlane(cnt[wid]);
  const int base = __builtin_amdgcn_readfirstlane(off[wid]);
  const unsigned* xs = reinterpret_cast<const unsigned*>(A) + 64 + lane;

  unsigned ent = (lane < deg) ? bucket[base + lane] : 0u;
  const int dcap = min(deg, 64);

  float l0 = 0.f, h0 = 0.f, l1 = 0.f, h1 = 0.f;
  int j = 0;
  for (; j + 7 < dcap; j += 8) {
    unsigned u[8];
#pragma unroll
    for (int k = 0; k < 8; ++k) {
      int s = __builtin_amdgcn_readlane((int)ent, j + k);
      u[k] = xs[(size_t)s * 128];
    }
#pragma unroll
    for (int k = 0; k < 8; ++k) {
      if (k & 1) { l1 += lo_f(u[k]); h1 += hi_f(u[k]); }
      else       { l0 += lo_f(u[k]); h0 += hi_f(u[k]); }
    }
  }
  for (; j < dcap; ++j) {
    int s = __builtin_amdgcn_readlane((int)ent, j);
    unsigned u0 = xs[(size_t)s * 128];
    l0 += lo_f(u0); h0 += hi_f(u0);
  }
  for (; j < deg; ++j) {
    int s = __builtin_amdgcn_readfirstlane((int)bucket[base + j]);
    unsigned u0 = xs[(size_t)s * 128];
    l0 += lo_f(u0); h0 += hi_f(u0);
  }
  const float r = 1.0f / fmaxf((float)deg, 1.0f);
  const float av = (l0 + l1) * r;
  const float bv = (h0 + h1) * r;
  *dst = (unsigned)f2bf(av) | ((unsigned)f2bf(bv) << 16);
}

// ---------------------------------------------------------------------------
// K4: MFMA GEMM + fused bias/relu/row-masked column-sum -> per-wave partials
// ---------------------------------------------------------------------------
__global__ __launch_bounds__(256) void mfma_kernel(
    const short* __restrict__ A, const short* __restrict__ Bpack,
    const float* __restrict__ bl, float* __restrict__ partial, int nnodes) {
  __shared__ short a_lds[64 * 256];
  const int tid = threadIdx.x;
  const int wave = tid >> 6, lane = tid & 63;
  const int mt = blockIdx.x;
  const size_t abase = (size_t)mt * 64 * 256;

#pragma unroll
  for (int r = 0; r < 8; ++r) {
    int i = tid + 256 * r;
    int row = i >> 5, kc = i & 31;
    bf16x8 v = *reinterpret_cast<const bf16x8*>(A + abase + row * 256 + kc * 8);
    int byte = (row * 512 + kc * 16) ^ ((row & 7) << 4);
    *reinterpret_cast<bf16x8*>(reinterpret_cast<char*>(a_lds) + byte) = v;
  }
  __syncthreads();

  f32x4 acc[8];
#pragma unroll
  for (int nt = 0; nt < 8; ++nt) acc[nt] = (f32x4){0.f, 0.f, 0.f, 0.f};

  const int arow = wave * 16 + (lane & 15);
  const int kgrp = lane >> 4;
  const bf16x8* Bp = reinterpret_cast<const bf16x8*>(Bpack);

#pragma unroll
  for (int ks = 0; ks < 8; ++ks) {
    int byte = (arow * 512 + (ks * 32 + kgrp * 8) * 2) ^ ((arow & 7) << 4);
    bf16x8 a = *reinterpret_cast<const bf16x8*>(reinterpret_cast<char*>(a_lds) + byte);
#pragma unroll
    for (int nt = 0; nt < 8; ++nt) {
      bf16x8 b = Bp[(ks * 8 + nt) * 64 + lane];
      acc[nt] = __builtin_amdgcn_mfma_f32_16x16x32_bf16(a, b, acc[nt], 0, 0, 0);
    }
  }

  const int col16 = lane & 15;
  const int rowbase = mt * 64 + wave * 16 + kgrp * 4;
#pragma unroll
  for (int nt = 0; nt < 8; ++nt) {
    const int c = nt * 16 + col16;
    const float bb = bl[c];
    float s = 0.f;
#pragma unroll
    for (int rg = 0; rg < 4; ++rg) {
      float v = fmaxf(acc[nt][rg] + bb, 0.f);
      s += (rowbase + rg < nnodes) ? v : 0.f;
    }
    s += __shfl_xor(s, 16);
    s += __shfl_xor(s, 32);
    if (kgrp == 0) partial[((size_t)mt * 4 + wave) * DIM + c] = s;
  }
}

// ---------------------------------------------------------------------------
// K5a: parallel row-reduction of partial [nrows][128] -> red[128][128]
// ---------------------------------------------------------------------------
__global__ __launch_bounds__(256) void red1_kernel(
    const float* __restrict__ partial, int nrows, float* __restrict__ red) {
  __shared__ float tmp[128];
  const int c = threadIdx.x & 127;
  const int half = threadIdx.x >> 7;
  const int chunk = (nrows + 127) / 128;
  const int r0 = blockIdx.x * chunk;
  const int r1 = min(r0 + chunk, nrows);
  float s = 0.f;
  for (int r = r0 + half; r < r1; r += 2) s += partial[(size_t)r * DIM + c];
  if (half) tmp[c] = s;
  __syncthreads();
  if (!half) red[(size_t)blockIdx.x * DIM + c] = s + tmp[c];
}

// ---------------------------------------------------------------------------
// K5b: sum red's 128 rows, dot with W_out, scale, add bias.
// ---------------------------------------------------------------------------
__global__ __launch_bounds__(256) void red2_kernel(
    const float* __restrict__ red, const float* __restrict__ Wout,
    const float* __restrict__ bout, float* __restrict__ out, int nnodes) {
  __shared__ float tmp[128];
  __shared__ float prod[128];
  const int c = threadIdx.x & 127;
  const int half = threadIdx.x >> 7;
  float s = 0.f;
  for (int r = half; r < 128; r += 2) s += red[(size_t)r * DIM + c];
  if (half) tmp[c] = s;
  __syncthreads();
  if (!half) prod[c] = (s + tmp[c]) * Wout[c];
  __syncthreads();
  if (threadIdx.x == 0) {
    float v = 0.f;
    for (int i = 0; i < 128; ++i) v += prod[i];
    out[0] = v / (float)nnodes + bout[0];
  }
}

extern "C" void kernel_launch(void* const* d_in, const int* in_sizes, int n_in,
                              void* d_out, int out_size, void* d_ws, size_t ws_size,
                              hipStream_t stream) {
  const float* x    = (const float*)d_in[0];   // x_ligand [N,128]
  const int*   ei   = (const int*)d_in[4];     // ei_ll [2,E]
  const float* Wl   = (const float*)d_in[11];  // Wl_ll [128,128]
  const float* bl   = (const float*)d_in[12];  // bl_ll [128]
  const float* Wr   = (const float*)d_in[13];  // Wr_ll [128,128]
  const float* Wout = (const float*)d_in[14];  // W_out [128,1]
  const float* bout = (const float*)d_in[15];  // b_out [1]

  const int nnodes = in_sizes[0] / DIM;
  const int E = in_sizes[4] / 2;
  const int mtiles = (nnodes + 63) / 64;       // 782 == #regions
  const int mpad = mtiles * 64;                // 50048
  const int nchunk = (E + EPB - 1) / EPB;      // 196

  // ws layout: [chunkbuf nchunk*EPB u32][startsT nchunk*1024][countsT nchunk*1024]
  //            [csr mtiles*RCAP u32][cnt mpad][off mpad][A mpad*256 bf16]
  //            [Bpack 32768 bf16][red 128*128 f32]
  // partial (mtiles*4*128 f32 = 1.6MB) aliases chunkbuf (dead after compact).
  unsigned* chunkbuf = (unsigned*)d_ws;
  int*      startsT  = (int*)(chunkbuf + (size_t)nchunk * EPB);
  int*      countsT  = startsT + (size_t)nchunk * NRBIN;
  unsigned* csr      = (unsigned*)(countsT + (size_t)nchunk * NRBIN);
  int*      cnt      = (int*)(csr + (size_t)mtiles * RCAP);
  int*      off      = cnt + mpad;
  short*    A        = (short*)(off + mpad);
  short*    Bpack    = A + (size_t)mpad * 256;
  float*    red      = (float*)(Bpack + 32768);
  float*    partial  = (float*)chunkbuf;  // alias

  const int xb = mpad / 8;  // xcast blocks (mpad*32/256)
  prep_kernel<<<xb + 16, 256, 0, stream>>>(x, A, Wl, Wr, Bpack, nnodes, mpad, xb);

  partition_kernel<<<nchunk, 256, 0, stream>>>(ei, chunkbuf, startsT, countsT, E);

  compact_kernel<<<mtiles, 256, 0, stream>>>(chunkbuf, startsT, countsT, nchunk,
                                             csr, cnt, off);

  agg_kernel<<<(mpad + 3) / 4, 256, 0, stream>>>(cnt, off, csr, A, nnodes, mpad);

  mfma_kernel<<<mtiles, 256, 0, stream>>>(A, Bpack, bl, partial, nnodes);

  red1_kernel<<<128, 256, 0, stream>>>(partial, mtiles * 4, red);
  red2_kernel<<<1, 256, 0, stream>>>(red, Wout, bout, (float*)d_out, nnodes);
}

// Round 13
// 91.000 us; speedup vs baseline: 1.4138x; 1.0456x over previous
//
#include <hip/hip_runtime.h>
#include <hip/hip_bf16.h>

#define DIM 128
#define EPB 4096     // edges per partition chunk/block
#define NRBIN 1024   // region bins (mtiles=782 padded to pow2; 10 bits)
#define RCAP 1280    // final per-region CSR capacity (mean 1023 + 8 sigma)

typedef __attribute__((ext_vector_type(8))) short bf16x8;
typedef __attribute__((ext_vector_type(4))) float f32x4;
typedef __attribute__((ext_vector_type(4))) short short4v;
typedef __attribute__((ext_vector_type(4))) int int4v;

__device__ inline unsigned short f2bf(float f) {
  union { float f; unsigned u; } v; v.f = f;
  return (unsigned short)((v.u + 0x7FFFu + ((v.u >> 16) & 1u)) >> 16);
}
__device__ inline float lo_f(unsigned u) {
  union { unsigned u; float f; } v; v.u = u << 16; return v.f;
}
__device__ inline float hi_f(unsigned u) {
  union { unsigned u; float f; } v; v.u = u & 0xFFFF0000u; return v.f;
}

// ---------------------------------------------------------------------------
// K1 "prep_part": fused partition + xcast + bpack (mutually independent; one
// launch, roles by blockIdx). Partition: atomic-free per-chunk LDS counting
// sort by region, dense coalesced writeback (round-12 verified: kills the
// 28MB atomic write-through). xcast/bpack stream under partition's LDS phase.
// ---------------------------------------------------------------------------
__global__ __launch_bounds__(256) void prep_part_kernel(
    const int* __restrict__ ei, unsigned* __restrict__ chunkbuf,
    int* __restrict__ startsT, int* __restrict__ countsT, int E, int nchunk,
    const float* __restrict__ x, short* __restrict__ A,
    const float* __restrict__ Wl, const float* __restrict__ Wr,
    short* __restrict__ Bpack, int nnodes, int mpad, int xb) {
  __shared__ unsigned uns[EPB];
  __shared__ unsigned srt[EPB];
  __shared__ int lhist[NRBIN];
  __shared__ int lstart[NRBIN];
  __shared__ int tsum[256];
  const int tid = threadIdx.x;
  const int bid = blockIdx.x;

  if (bid >= nchunk) {
    if (bid < nchunk + xb) {
      // xcast: cast x -> bf16 into x-half of A ([mpad][256] bf16, k>=128 = x)
      int t = (bid - nchunk) * 256 + tid;
      int node = t >> 5;
      if (node >= mpad) return;
      int c = (t & 31) * 4;
      short4v o = (short4v){0, 0, 0, 0};
      if (node < nnodes) {
        float4 v = *reinterpret_cast<const float4*>(x + (size_t)node * DIM + c);
        o.x = (short)f2bf(v.x); o.y = (short)f2bf(v.y);
        o.z = (short)f2bf(v.z); o.w = (short)f2bf(v.w);
      }
      *reinterpret_cast<short4v*>(A + (size_t)node * 256 + 128 + c) = o;
    } else {
      // bpack: B = [[Wl];[Wr]] (256x128) into MFMA fragment order
      int t = (bid - nchunk - xb) * 256 + tid;
      if (t >= 4096) return;
      int lane = t & 63, nt = (t >> 6) & 7, ks = t >> 9;
      int c = nt * 16 + (lane & 15);
      int kb = ks * 32 + ((lane >> 4) << 3);
      bf16x8 o;
#pragma unroll
      for (int j = 0; j < 8; ++j) {
        int k = kb + j;
        float v = (k < DIM) ? Wl[k * DIM + c] : Wr[(k - DIM) * DIM + c];
        o[j] = (short)f2bf(v);
      }
      reinterpret_cast<bf16x8*>(Bpack)[(ks * 8 + nt) * 64 + lane] = o;
    }
    return;
  }

  // ------------------- partition role -------------------
  const int chunk = bid;
  const int base = chunk * EPB;
  const int count = min(EPB, E - base);

#pragma unroll
  for (int r = 0; r < NRBIN / 256; ++r) lhist[tid + 256 * r] = 0;
  __syncthreads();

  // phase A: load edges, pack entries, LDS histogram by region
  for (int r = 0; r < EPB / 1024; ++r) {
    int i = r * 1024 + tid * 4;
    if (i + 3 < count) {
      int4 s4 = *reinterpret_cast<const int4*>(ei + base + i);
      int4 d4 = *reinterpret_cast<const int4*>(ei + E + base + i);
      int ss[4] = {s4.x, s4.y, s4.z, s4.w};
      int dd[4] = {d4.x, d4.y, d4.z, d4.w};
#pragma unroll
      for (int k = 0; k < 4; ++k) {
        unsigned reg = (unsigned)dd[k] >> 6;
        uns[i + k] = (reg << 22) | ((unsigned)(dd[k] & 63) << 16) | (unsigned)ss[k];
        atomicAdd(&lhist[reg], 1);
      }
    } else {
      for (int k = 0; k < 4; ++k) {
        if (i + k < count) {
          int s = ei[base + i + k], d = ei[E + base + i + k];
          unsigned reg = (unsigned)d >> 6;
          uns[i + k] = (reg << 22) | ((unsigned)(d & 63) << 16) | (unsigned)s;
          atomicAdd(&lhist[reg], 1);
        }
      }
    }
  }
  __syncthreads();

  // exclusive scan of lhist (4 bins/thread + block scan of thread sums)
  int h0 = lhist[tid * 4], h1 = lhist[tid * 4 + 1];
  int h2 = lhist[tid * 4 + 2], h3 = lhist[tid * 4 + 3];
  int local = h0 + h1 + h2 + h3;
  tsum[tid] = local;
  __syncthreads();
  for (int o = 1; o < 256; o <<= 1) {
    int t = (tid >= o) ? tsum[tid - o] : 0;
    __syncthreads();
    tsum[tid] += t;
    __syncthreads();
  }
  int tb = tsum[tid] - local;
  lstart[tid * 4]     = tb;
  lstart[tid * 4 + 1] = tb + h0;
  lstart[tid * 4 + 2] = tb + h0 + h1;
  lstart[tid * 4 + 3] = tb + h0 + h1 + h2;
  lhist[tid * 4] = 0; lhist[tid * 4 + 1] = 0;
  lhist[tid * 4 + 2] = 0; lhist[tid * 4 + 3] = 0;  // becomes fill counter
  __syncthreads();

  // phase B: scatter into region-sorted LDS order
  for (int i = tid; i < count; i += 256) {
    unsigned e = uns[i];
    unsigned reg = e >> 22;
    int pos = lstart[reg] + atomicAdd(&lhist[reg], 1);
    srt[pos] = e;
  }
  __syncthreads();

  // dense writeback: sorted chunk (int4) + starts/counts rows
  for (int r = 0; r < EPB / 1024; ++r) {
    int i = r * 1024 + tid * 4;
    if (i + 3 < count) {
      int4v v = {(int)srt[i], (int)srt[i + 1], (int)srt[i + 2], (int)srt[i + 3]};
      *reinterpret_cast<int4v*>(chunkbuf + (size_t)chunk * EPB + i) = v;
    } else {
      for (int k = 0; k < 4; ++k)
        if (i + k < count) chunkbuf[(size_t)chunk * EPB + i + k] = srt[i + k];
    }
  }
  for (int r = tid; r < NRBIN; r += 256) {
    startsT[(size_t)chunk * NRBIN + r] = lstart[r];
    countsT[(size_t)chunk * NRBIN + r] = lhist[r];
  }
}

// ---------------------------------------------------------------------------
// K2: per-region merge of per-chunk runs (one chunk per thread, prefix via
// LDS scan) + node-level counting sort -> final CSR + cnt/off.
// ---------------------------------------------------------------------------
__global__ __launch_bounds__(256) void compact_kernel(
    const unsigned* __restrict__ chunkbuf, const int* __restrict__ startsT,
    const int* __restrict__ countsT, int nchunk, unsigned* __restrict__ csr,
    int* __restrict__ cnt, int* __restrict__ off) {
  __shared__ unsigned raw[RCAP];
  __shared__ unsigned srt[RCAP];
  __shared__ int h[64];
  __shared__ int start[64];
  __shared__ int tsum[256];
  const int region = blockIdx.x;
  const int tid = threadIdx.x;

  int cn = 0, st = 0;
  if (tid < nchunk) {
    cn = countsT[(size_t)tid * NRBIN + region];
    st = startsT[(size_t)tid * NRBIN + region];
  }
  tsum[tid] = cn;
  __syncthreads();
  for (int o = 1; o < 256; o <<= 1) {
    int t = (tid >= o) ? tsum[tid - o] : 0;
    __syncthreads();
    tsum[tid] += t;
    __syncthreads();
  }
  const int pfx = tsum[tid] - cn;
  int total = min(tsum[255], RCAP);

  const unsigned* src = chunkbuf + (size_t)tid * EPB + st;
  for (int j = 0; j < cn && pfx + j < RCAP; ++j) raw[pfx + j] = src[j];
  if (tid < 64) h[tid] = 0;
  __syncthreads();

  for (int i = tid; i < total; i += 256) atomicAdd(&h[(raw[i] >> 16) & 63], 1);
  __syncthreads();
  if (tid == 0) {
    int s = 0;
    for (int i = 0; i < 64; ++i) { start[i] = s; s += h[i]; }
  }
  __syncthreads();
  if (tid < 64) {
    int node = region * 64 + tid;
    cnt[node] = h[tid];
    off[node] = region * RCAP + start[tid];
    h[tid] = 0;  // becomes fill counter
  }
  __syncthreads();
  for (int i = tid; i < total; i += 256) {
    unsigned e = raw[i];
    int d = (e >> 16) & 63;
    int pos = start[d] + atomicAdd(&h[d], 1);
    srt[pos] = e & 0xFFFFu;  // keep only src
  }
  __syncthreads();
  for (int i = tid; i < total; i += 256) csr[(size_t)region * RCAP + i] = srt[i];
}

// ---------------------------------------------------------------------------
// K3: mean-aggregation, one wave per node (50048 waves of TLP). Src list via
// ONE coalesced wave load + readlane broadcast; 16-deep row-gather MLP
// (deg mean=16 -> typically ONE L3 round-trip instead of two).
// ---------------------------------------------------------------------------
__global__ __launch_bounds__(256, 4) void agg_kernel(
    const int* __restrict__ cnt, const int* __restrict__ off,
    const unsigned* __restrict__ bucket, short* __restrict__ A,
    int nnodes, int mpad) {
  const int wid = (blockIdx.x * 256 + threadIdx.x) >> 6;
  const int lane = threadIdx.x & 63;
  if (wid >= mpad) return;
  unsigned* dst = reinterpret_cast<unsigned*>(A + (size_t)wid * 256) + lane;
  if (wid >= nnodes) { *dst = 0u; return; }
  const int deg  = __builtin_amdgcn_readfirstlane(cnt[wid]);
  const int base = __builtin_amdgcn_readfirstlane(off[wid]);
  const unsigned* xs = reinterpret_cast<const unsigned*>(A) + 64 + lane;

  unsigned ent = (lane < deg) ? bucket[base + lane] : 0u;
  const int dcap = min(deg, 64);

  float l0 = 0.f, h0 = 0.f, l1 = 0.f, h1 = 0.f;
  int j = 0;
  for (; j + 15 < dcap; j += 16) {
    unsigned u[16];
#pragma unroll
    for (int k = 0; k < 16; ++k) {
      int s = __builtin_amdgcn_readlane((int)ent, j + k);
      u[k] = xs[(size_t)s * 128];
    }
#pragma unroll
    for (int k = 0; k < 16; ++k) {
      if (k & 1) { l1 += lo_f(u[k]); h1 += hi_f(u[k]); }
      else       { l0 += lo_f(u[k]); h0 += hi_f(u[k]); }
    }
  }
  for (; j + 7 < dcap; j += 8) {
    unsigned u[8];
#pragma unroll
    for (int k = 0; k < 8; ++k) {
      int s = __builtin_amdgcn_readlane((int)ent, j + k);
      u[k] = xs[(size_t)s * 128];
    }
#pragma unroll
    for (int k = 0; k < 8; ++k) {
      if (k & 1) { l1 += lo_f(u[k]); h1 += hi_f(u[k]); }
      else       { l0 += lo_f(u[k]); h0 += hi_f(u[k]); }
    }
  }
  for (; j < dcap; ++j) {
    int s = __builtin_amdgcn_readlane((int)ent, j);
    unsigned u0 = xs[(size_t)s * 128];
    l0 += lo_f(u0); h0 += hi_f(u0);
  }
  for (; j < deg; ++j) {
    int s = __builtin_amdgcn_readfirstlane((int)bucket[base + j]);
    unsigned u0 = xs[(size_t)s * 128];
    l0 += lo_f(u0); h0 += hi_f(u0);
  }
  const float r = 1.0f / fmaxf((float)deg, 1.0f);
  const float av = (l0 + l1) * r;
  const float bv = (h0 + h1) * r;
  *dst = (unsigned)f2bf(av) | ((unsigned)f2bf(bv) << 16);
}

// ---------------------------------------------------------------------------
// K4: MFMA GEMM + fused bias/relu/row-masked column-sum -> per-wave partials
// ---------------------------------------------------------------------------
__global__ __launch_bounds__(256) void mfma_kernel(
    const short* __restrict__ A, const short* __restrict__ Bpack,
    const float* __restrict__ bl, float* __restrict__ partial, int nnodes) {
  __shared__ short a_lds[64 * 256];
  const int tid = threadIdx.x;
  const int wave = tid >> 6, lane = tid & 63;
  const int mt = blockIdx.x;
  const size_t abase = (size_t)mt * 64 * 256;

#pragma unroll
  for (int r = 0; r < 8; ++r) {
    int i = tid + 256 * r;
    int row = i >> 5, kc = i & 31;
    bf16x8 v = *reinterpret_cast<const bf16x8*>(A + abase + row * 256 + kc * 8);
    int byte = (row * 512 + kc * 16) ^ ((row & 7) << 4);
    *reinterpret_cast<bf16x8*>(reinterpret_cast<char*>(a_lds) + byte) = v;
  }
  __syncthreads();

  f32x4 acc[8];
#pragma unroll
  for (int nt = 0; nt < 8; ++nt) acc[nt] = (f32x4){0.f, 0.f, 0.f, 0.f};

  const int arow = wave * 16 + (lane & 15);
  const int kgrp = lane >> 4;
  const bf16x8* Bp = reinterpret_cast<const bf16x8*>(Bpack);

#pragma unroll
  for (int ks = 0; ks < 8; ++ks) {
    int byte = (arow * 512 + (ks * 32 + kgrp * 8) * 2) ^ ((arow & 7) << 4);
    bf16x8 a = *reinterpret_cast<const bf16x8*>(reinterpret_cast<char*>(a_lds) + byte);
#pragma unroll
    for (int nt = 0; nt < 8; ++nt) {
      bf16x8 b = Bp[(ks * 8 + nt) * 64 + lane];
      acc[nt] = __builtin_amdgcn_mfma_f32_16x16x32_bf16(a, b, acc[nt], 0, 0, 0);
    }
  }

  const int col16 = lane & 15;
  const int rowbase = mt * 64 + wave * 16 + kgrp * 4;
#pragma unroll
  for (int nt = 0; nt < 8; ++nt) {
    const int c = nt * 16 + col16;
    const float bb = bl[c];
    float s = 0.f;
#pragma unroll
    for (int rg = 0; rg < 4; ++rg) {
      float v = fmaxf(acc[nt][rg] + bb, 0.f);
      s += (rowbase + rg < nnodes) ? v : 0.f;
    }
    s += __shfl_xor(s, 16);
    s += __shfl_xor(s, 32);
    if (kgrp == 0) partial[((size_t)mt * 4 + wave) * DIM + c] = s;
  }
}

// ---------------------------------------------------------------------------
// K5a: parallel row-reduction of partial [nrows][128] -> red[128][128]
// ---------------------------------------------------------------------------
__global__ __launch_bounds__(256) void red1_kernel(
    const float* __restrict__ partial, int nrows, float* __restrict__ red) {
  __shared__ float tmp[128];
  const int c = threadIdx.x & 127;
  const int half = threadIdx.x >> 7;
  const int chunk = (nrows + 127) / 128;
  const int r0 = blockIdx.x * chunk;
  const int r1 = min(r0 + chunk, nrows);
  float s = 0.f;
  for (int r = r0 + half; r < r1; r += 2) s += partial[(size_t)r * DIM + c];
  if (half) tmp[c] = s;
  __syncthreads();
  if (!half) red[(size_t)blockIdx.x * DIM + c] = s + tmp[c];
}

// ---------------------------------------------------------------------------
// K5b: sum red's 128 rows, dot with W_out, scale, add bias.
// ---------------------------------------------------------------------------
__global__ __launch_bounds__(256) void red2_kernel(
    const float* __restrict__ red, const float* __restrict__ Wout,
    const float* __restrict__ bout, float* __restrict__ out, int nnodes) {
  __shared__ float tmp[128];
  __shared__ float prod[128];
  const int c = threadIdx.x & 127;
  const int half = threadIdx.x >> 7;
  float s = 0.f;
  for (int r = half; r < 128; r += 2) s += red[(size_t)r * DIM + c];
  if (half) tmp[c] = s;
  __syncthreads();
  if (!half) prod[c] = (s + tmp[c]) * Wout[c];
  __syncthreads();
  if (threadIdx.x == 0) {
    float v = 0.f;
    for (int i = 0; i < 128; ++i) v += prod[i];
    out[0] = v / (float)nnodes + bout[0];
  }
}

extern "C" void kernel_launch(void* const* d_in, const int* in_sizes, int n_in,
                              void* d_out, int out_size, void* d_ws, size_t ws_size,
                              hipStream_t stream) {
  const float* x    = (const float*)d_in[0];   // x_ligand [N,128]
  const int*   ei   = (const int*)d_in[4];     // ei_ll [2,E]
  const float* Wl   = (const float*)d_in[11];  // Wl_ll [128,128]
  const float* bl   = (const float*)d_in[12];  // bl_ll [128]
  const float* Wr   = (const float*)d_in[13];  // Wr_ll [128,128]
  const float* Wout = (const float*)d_in[14];  // W_out [128,1]
  const float* bout = (const float*)d_in[15];  // b_out [1]

  const int nnodes = in_sizes[0] / DIM;
  const int E = in_sizes[4] / 2;
  const int mtiles = (nnodes + 63) / 64;       // 782 == #regions
  const int mpad = mtiles * 64;                // 50048
  const int nchunk = (E + EPB - 1) / EPB;      // 196

  // ws layout: [chunkbuf nchunk*EPB u32][startsT nchunk*1024][countsT nchunk*1024]
  //            [csr mtiles*RCAP u32][cnt mpad][off mpad][A mpad*256 bf16]
  //            [Bpack 32768 bf16][red 128*128 f32]
  // partial (mtiles*4*128 f32 = 1.6MB) aliases chunkbuf (dead after compact).
  unsigned* chunkbuf = (unsigned*)d_ws;
  int*      startsT  = (int*)(chunkbuf + (size_t)nchunk * EPB);
  int*      countsT  = startsT + (size_t)nchunk * NRBIN;
  unsigned* csr      = (unsigned*)(countsT + (size_t)nchunk * NRBIN);
  int*      cnt      = (int*)(csr + (size_t)mtiles * RCAP);
  int*      off      = cnt + mpad;
  short*    A        = (short*)(off + mpad);
  short*    Bpack    = A + (size_t)mpad * 256;
  float*    red      = (float*)(Bpack + 32768);
  float*    partial  = (float*)chunkbuf;  // alias

  const int xb = mpad / 8;  // xcast blocks (mpad*32/256)
  prep_part_kernel<<<nchunk + xb + 16, 256, 0, stream>>>(
      ei, chunkbuf, startsT, countsT, E, nchunk,
      x, A, Wl, Wr, Bpack, nnodes, mpad, xb);

  compact_kernel<<<mtiles, 256, 0, stream>>>(chunkbuf, startsT, countsT, nchunk,
                                             csr, cnt, off);

  agg_kernel<<<(mpad + 3) / 4, 256, 0, stream>>>(cnt, off, csr, A, nnodes, mpad);

  mfma_kernel<<<mtiles, 256, 0, stream>>>(A, Bpack, bl, partial, nnodes);

  red1_kernel<<<128, 256, 0, stream>>>(partial, mtiles * 4, red);
  red2_kernel<<<1, 256, 0, stream>>>(red, Wout, bout, (float*)d_out, nnodes);
}